// Round 1
// baseline (357.410 us; speedup 1.0000x reference)
//
#include <hip/hip_runtime.h>
#include <hip/hip_bf16.h>
#include <math.h>

// Problem constants (from reference setup_inputs)
#define B_  4
#define C_  64
#define H_  128
#define W_  128
#define O_  64
#define K2_ 9
#define HW_ (H_ * W_)

// -------------------------------------------------------------------------
// K0: repack weight (O, C, K2) -> (K2, C, O) so that for fixed (k, c) the 64
// output-channel weights are contiguous (enables s_load_dwordx16 in K2).
// -------------------------------------------------------------------------
__global__ __launch_bounds__(256) void repack_weight(
    const float* __restrict__ weight, float* __restrict__ wp)
{
    int t = blockIdx.x * 256 + threadIdx.x;     // 0 .. O*C*K2-1 = 36863
    if (t >= O_ * C_ * K2_) return;
    int o = t / (C_ * K2_);
    int c = (t / K2_) % C_;
    int k = t % K2_;
    wp[(k * C_ + c) * O_ + o] = weight[t];
}

// -------------------------------------------------------------------------
// K1: fused offset+mask conv. One thread per output pixel computes all 27
// output channels (18 offsets + 9 mask logits). x neighborhood (9 values per
// input channel) kept in registers and reused across the 27 outputs.
// Weight indices are wave-uniform -> scalar loads.
// -------------------------------------------------------------------------
__global__ __launch_bounds__(256) void conv_offsets_mask(
    const float* __restrict__ x,
    const float* __restrict__ ow, const float* __restrict__ ob,
    const float* __restrict__ mw, const float* __restrict__ mb,
    float* __restrict__ off, float* __restrict__ mask)
{
    int tid = blockIdx.x * 256 + threadIdx.x;   // B*H*W = 65536 threads
    int b = tid >> 14;
    int h = (tid >> 7) & (H_ - 1);
    int w = tid & (W_ - 1);

    float acc[27];
#pragma unroll
    for (int i = 0; i < 18; ++i) acc[i] = ob[i];
#pragma unroll
    for (int i = 0; i < 9; ++i) acc[18 + i] = mb[i];

    const float* xb = x + (size_t)b * (C_ * HW_) + h * W_ + w;

    for (int c = 0; c < C_; ++c) {
        const float* xp = xb + c * HW_;
        float v[9];
#pragma unroll
        for (int i = 0; i < 3; ++i) {
            int y = h - 1 + i;
            bool vy = (y >= 0) && (y < H_);
#pragma unroll
            for (int j = 0; j < 3; ++j) {
                int xx = w - 1 + j;
                bool vx = (xx >= 0) && (xx < W_);
                v[i * 3 + j] = (vy && vx) ? xp[(i - 1) * W_ + (j - 1)] : 0.0f;
            }
        }
#pragma unroll
        for (int oc = 0; oc < 18; ++oc) {
#pragma unroll
            for (int k = 0; k < 9; ++k)
                acc[oc] = fmaf(ow[(oc * C_ + c) * 9 + k], v[k], acc[oc]);
        }
#pragma unroll
        for (int oc = 0; oc < 9; ++oc) {
#pragma unroll
            for (int k = 0; k < 9; ++k)
                acc[18 + oc] = fmaf(mw[(oc * C_ + c) * 9 + k], v[k], acc[18 + oc]);
        }
    }

    int pix = h * W_ + w;
#pragma unroll
    for (int oc = 0; oc < 18; ++oc)
        off[((size_t)b * 18 + oc) * HW_ + pix] = acc[oc];
#pragma unroll
    for (int oc = 0; oc < 9; ++oc) {
        float s = 2.0f / (1.0f + __expf(-acc[18 + oc]));
        mask[((size_t)b * 9 + oc) * HW_ + pix] = s;
    }
}

// -------------------------------------------------------------------------
// K2: deformable conv. One thread per output pixel, all 64 output channels
// accumulated in registers. Per tap k: bilinear corner indices + weights
// (validity and mask folded into the weights). Per channel c: 4 gathers ->
// sample s, then 64 FMAs against packed (k,c,o) weights (wave-uniform ->
// SGPR-resident via s_load).
// -------------------------------------------------------------------------
__global__ __launch_bounds__(256) void deform_conv(
    const float* __restrict__ x,
    const float* __restrict__ off, const float* __restrict__ mask,
    const float* __restrict__ wp,  float* __restrict__ out)
{
    int tid = blockIdx.x * 256 + threadIdx.x;   // B*H*W = 65536 threads
    int b = tid >> 14;
    int h = (tid >> 7) & (H_ - 1);
    int w = tid & (W_ - 1);
    int pix = h * W_ + w;

    float acc[O_];
#pragma unroll
    for (int o = 0; o < O_; ++o) acc[o] = 0.0f;

    const float* xb = x + (size_t)b * (C_ * HW_);

#pragma unroll
    for (int k = 0; k < K2_; ++k) {
        int ky = k / 3, kx = k % 3;
        float dy = off[((size_t)b * 18 + 2 * k)     * HW_ + pix];
        float dx = off[((size_t)b * 18 + 2 * k + 1) * HW_ + pix];
        float m  = mask[((size_t)b * 9 + k) * HW_ + pix];

        float py = (float)(h - 1 + ky) + dy;
        float px = (float)(w - 1 + kx) + dx;
        float y0f = floorf(py), x0f = floorf(px);
        float fy = py - y0f, fx = px - x0f;
        int y0 = (int)y0f, x0 = (int)x0f;
        int y1 = y0 + 1, x1 = x0 + 1;

        bool vy0 = (y0 >= 0) && (y0 < H_);
        bool vy1 = (y1 >= 0) && (y1 < H_);
        bool vx0 = (x0 >= 0) && (x0 < W_);
        bool vx1 = (x1 >= 0) && (x1 < W_);

        float w00 = (1.0f - fy) * (1.0f - fx) * m; if (!(vy0 && vx0)) w00 = 0.0f;
        float w01 = (1.0f - fy) * fx          * m; if (!(vy0 && vx1)) w01 = 0.0f;
        float w10 = fy * (1.0f - fx)          * m; if (!(vy1 && vx0)) w10 = 0.0f;
        float w11 = fy * fx                   * m; if (!(vy1 && vx1)) w11 = 0.0f;

        int y0c = min(max(y0, 0), H_ - 1);
        int y1c = min(max(y1, 0), H_ - 1);
        int x0c = min(max(x0, 0), W_ - 1);
        int x1c = min(max(x1, 0), W_ - 1);

        int i00 = y0c * W_ + x0c;
        int i01 = y0c * W_ + x1c;
        int i10 = y1c * W_ + x0c;
        int i11 = y1c * W_ + x1c;

        for (int c = 0; c < C_; ++c) {
            const float* xp = xb + c * HW_;
            float s = xp[i00] * w00;
            s = fmaf(xp[i01], w01, s);
            s = fmaf(xp[i10], w10, s);
            s = fmaf(xp[i11], w11, s);
            const float* wrow = wp + ((size_t)k * C_ + c) * O_;
#pragma unroll
            for (int o = 0; o < O_; ++o)
                acc[o] = fmaf(s, wrow[o], acc[o]);
        }
    }

    float* op = out + (size_t)b * (O_ * HW_) + pix;
#pragma unroll
    for (int o = 0; o < O_; ++o) op[o * HW_] = acc[o];
}

// -------------------------------------------------------------------------
extern "C" void kernel_launch(void* const* d_in, const int* in_sizes, int n_in,
                              void* d_out, int out_size, void* d_ws, size_t ws_size,
                              hipStream_t stream)
{
    const float* x        = (const float*)d_in[0];
    const float* offset_w = (const float*)d_in[1];
    const float* offset_b = (const float*)d_in[2];
    const float* mod_w    = (const float*)d_in[3];
    const float* mod_b    = (const float*)d_in[4];
    const float* weight   = (const float*)d_in[5];
    float* out = (float*)d_out;

    // Workspace layout (floats):
    //   off  : B*18*H*W = 1,179,648
    //   mask : B* 9*H*W =   589,824
    //   wp   : K2*C*O   =    36,864
    float* off_buf  = (float*)d_ws;
    float* mask_buf = off_buf + (size_t)B_ * 18 * HW_;
    float* wp       = mask_buf + (size_t)B_ * 9 * HW_;

    // K0: weight repack (O,C,K2) -> (K2,C,O)
    repack_weight<<<(O_ * C_ * K2_ + 255) / 256, 256, 0, stream>>>(weight, wp);

    // K1: offset + mask conv (one thread per pixel)
    conv_offsets_mask<<<(B_ * HW_) / 256, 256, 0, stream>>>(
        x, offset_w, offset_b, mod_w, mod_b, off_buf, mask_buf);

    // K2: deformable conv
    deform_conv<<<(B_ * HW_) / 256, 256, 0, stream>>>(
        x, off_buf, mask_buf, wp, out);
}

// Round 2
// 259.714 us; speedup vs baseline: 1.3762x; 1.3762x over previous
//
#include <hip/hip_runtime.h>
#include <hip/hip_bf16.h>
#include <math.h>

// Problem constants (from reference setup_inputs)
#define B_  4
#define C_  64
#define H_  128
#define W_  128
#define O_  64
#define K2_ 9
#define HW_ (H_ * W_)

// -------------------------------------------------------------------------
// K0: weight repacks.
//   wp  : (O,C,K2) -> (K2,C,O)       for K2's contraction (contiguous o-rows)
//   owp : ow(18,C,3,3)+mw(9,C,3,3) -> (C, 27*9)  c-major, contiguous per c
// -------------------------------------------------------------------------
__global__ __launch_bounds__(256) void repack_weights(
    const float* __restrict__ weight,
    const float* __restrict__ ow, const float* __restrict__ mw,
    float* __restrict__ wp, float* __restrict__ owp)
{
    int t = blockIdx.x * 256 + threadIdx.x;
    const int NWP = O_ * C_ * K2_;          // 36864
    const int NOWP = C_ * 27 * 9;           // 15552
    if (t < NWP) {
        int o = t / (C_ * K2_);
        int c = (t / K2_) % C_;
        int k = t % K2_;
        wp[(k * C_ + c) * O_ + o] = weight[t];
    } else if (t < NWP + NOWP) {
        int u = t - NWP;
        int c = u / (27 * 9);
        int oc = (u / 9) % 27;
        int k = u % 9;
        float v = (oc < 18) ? ow[((size_t)oc * C_ + c) * 9 + k]
                            : mw[((size_t)(oc - 18) * C_ + c) * 9 + k];
        owp[(size_t)c * 243 + oc * 9 + k] = v;
    }
}

// -------------------------------------------------------------------------
// K1: fused offset+mask conv. Block = 64 pixels x 4 c-groups (16 c each).
// Each thread accumulates 27 partial channels over its 16 input channels;
// LDS reduce across the 4 c-groups; first wave applies bias/sigmoid+store.
// Weights are c-major (owp) and wave-uniform -> s_load_dwordx16.
// -------------------------------------------------------------------------
__global__ __launch_bounds__(256) void conv_offsets_mask(
    const float* __restrict__ x,
    const float* __restrict__ owp,
    const float* __restrict__ ob, const float* __restrict__ mb,
    float* __restrict__ off, float* __restrict__ mask)
{
    int t = threadIdx.x;
    int px = t & 63;
    int cg = __builtin_amdgcn_readfirstlane(t >> 6);   // 0..3, uniform per wave

    int pixg = blockIdx.x * 64 + px;         // global pixel 0..65535
    int b = pixg >> 14;
    int pix = pixg & (HW_ - 1);
    int h = pix >> 7;
    int w = pix & (W_ - 1);

    bool vy[3], vx[3];
#pragma unroll
    for (int i = 0; i < 3; ++i) {
        vy[i] = (unsigned)(h - 1 + i) < (unsigned)H_;
        vx[i] = (unsigned)(w - 1 + i) < (unsigned)W_;
    }

    float acc[27];
#pragma unroll
    for (int i = 0; i < 27; ++i) acc[i] = 0.0f;

    const float* xbase = x + ((size_t)b * C_ + cg * 16) * HW_ + h * W_ + w;
    const float* wbase = owp + (size_t)(cg * 16) * 243;

#pragma unroll 2
    for (int ci = 0; ci < 16; ++ci) {
        const float* xp = xbase + ci * HW_;
        float v[9];
#pragma unroll
        for (int i = 0; i < 3; ++i)
#pragma unroll
            for (int j = 0; j < 3; ++j)
                v[i * 3 + j] = (vy[i] && vx[j]) ? xp[(i - 1) * W_ + (j - 1)] : 0.0f;

        const float* wrow = wbase + ci * 243;
#pragma unroll
        for (int oc = 0; oc < 27; ++oc)
#pragma unroll
            for (int kk = 0; kk < 9; ++kk)
                acc[oc] = fmaf(wrow[oc * 9 + kk], v[kk], acc[oc]);
    }

    __shared__ float red[27][4][64];         // 27.6 KB
#pragma unroll
    for (int oc = 0; oc < 27; ++oc) red[oc][cg][px] = acc[oc];
    __syncthreads();

    if (cg == 0) {
#pragma unroll
        for (int oc = 0; oc < 18; ++oc) {
            float s = red[oc][0][px] + red[oc][1][px] + red[oc][2][px] + red[oc][3][px] + ob[oc];
            off[((size_t)b * 18 + oc) * HW_ + pix] = s;
        }
#pragma unroll
        for (int oc = 0; oc < 9; ++oc) {
            float s = red[18 + oc][0][px] + red[18 + oc][1][px] + red[18 + oc][2][px] + red[18 + oc][3][px] + mb[oc];
            mask[((size_t)b * 9 + oc) * HW_ + pix] = 2.0f / (1.0f + __expf(-s));
        }
    }
}

// -------------------------------------------------------------------------
// K2: deformable conv. Block = 64 pixels; thread = (px, o-half, c-half):
//   og = (t>>6)&1 selects o in [og*32, og*32+32)
//   cg = t>>7    selects c in [cg*32, cg*32+32)
// acc[32] (no spill). LDS reduce combines the two c-halves.
// Weight rows wave-uniform (og,cg scalar) -> s_load + FMA-with-SGPR.
// -------------------------------------------------------------------------
__global__ __launch_bounds__(256) void deform_conv(
    const float* __restrict__ x,
    const float* __restrict__ off, const float* __restrict__ mask,
    const float* __restrict__ wp,  float* __restrict__ out)
{
    int t = threadIdx.x;
    int px = t & 63;
    int og = __builtin_amdgcn_readfirstlane((t >> 6) & 1);
    int cg = __builtin_amdgcn_readfirstlane(t >> 7);

    int pixg = blockIdx.x * 64 + px;
    int b = pixg >> 14;
    int pix = pixg & (HW_ - 1);
    int h = pix >> 7;
    int w = pix & (W_ - 1);

    float acc[32];
#pragma unroll
    for (int o = 0; o < 32; ++o) acc[o] = 0.0f;

    const float* xb = x + ((size_t)b * C_ + cg * 32) * HW_;

#pragma unroll 1
    for (int k = 0; k < K2_; ++k) {
        int ky = k / 3, kx = k % 3;
        float dy = off[((size_t)b * 18 + 2 * k)     * HW_ + pix];
        float dx = off[((size_t)b * 18 + 2 * k + 1) * HW_ + pix];
        float m  = mask[((size_t)b * 9 + k) * HW_ + pix];

        float py = (float)(h - 1 + ky) + dy;
        float px_ = (float)(w - 1 + kx) + dx;
        float y0f = floorf(py), x0f = floorf(px_);
        float fy = py - y0f, fx = px_ - x0f;
        int y0 = (int)y0f, x0 = (int)x0f;
        int y1 = y0 + 1, x1 = x0 + 1;

        bool vy0 = (unsigned)y0 < (unsigned)H_;
        bool vy1 = (unsigned)y1 < (unsigned)H_;
        bool vx0 = (unsigned)x0 < (unsigned)W_;
        bool vx1 = (unsigned)x1 < (unsigned)W_;

        float w00 = (1.0f - fy) * (1.0f - fx) * m; if (!(vy0 && vx0)) w00 = 0.0f;
        float w01 = (1.0f - fy) * fx          * m; if (!(vy0 && vx1)) w01 = 0.0f;
        float w10 = fy * (1.0f - fx)          * m; if (!(vy1 && vx0)) w10 = 0.0f;
        float w11 = fy * fx                   * m; if (!(vy1 && vx1)) w11 = 0.0f;

        int y0c = min(max(y0, 0), H_ - 1);
        int y1c = min(max(y1, 0), H_ - 1);
        int x0c = min(max(x0, 0), W_ - 1);
        int x1c = min(max(x1, 0), W_ - 1);

        int i00 = y0c * W_ + x0c;
        int i01 = y0c * W_ + x1c;
        int i10 = y1c * W_ + x0c;
        int i11 = y1c * W_ + x1c;

        const float* wkbase = wp + ((size_t)k * C_ + cg * 32) * O_ + og * 32;

#pragma unroll 4
        for (int c = 0; c < 32; ++c) {
            const float* xp = xb + c * HW_;
            float s = xp[i00] * w00;
            s = fmaf(xp[i01], w01, s);
            s = fmaf(xp[i10], w10, s);
            s = fmaf(xp[i11], w11, s);
            const float* wrow = wkbase + c * O_;
#pragma unroll
            for (int o = 0; o < 32; ++o)
                acc[o] = fmaf(s, wrow[o], acc[o]);
        }
    }

    __shared__ float red[64][2][64];         // 32 KB: [o][cgrp][px]
#pragma unroll
    for (int o = 0; o < 32; ++o) red[og * 32 + o][cg][px] = acc[o];
    __syncthreads();

    if (cg == 0) {
        float* op = out + (size_t)b * (O_ * HW_) + pix;
#pragma unroll
        for (int o = 0; o < 32; ++o) {
            int oc = og * 32 + o;
            op[(size_t)oc * HW_] = red[oc][0][px] + red[oc][1][px];
        }
    }
}

// -------------------------------------------------------------------------
extern "C" void kernel_launch(void* const* d_in, const int* in_sizes, int n_in,
                              void* d_out, int out_size, void* d_ws, size_t ws_size,
                              hipStream_t stream)
{
    const float* x        = (const float*)d_in[0];
    const float* offset_w = (const float*)d_in[1];
    const float* offset_b = (const float*)d_in[2];
    const float* mod_w    = (const float*)d_in[3];
    const float* mod_b    = (const float*)d_in[4];
    const float* weight   = (const float*)d_in[5];
    float* out = (float*)d_out;

    // Workspace layout (floats):
    //   off  : B*18*H*W = 1,179,648
    //   mask : B* 9*H*W =   589,824
    //   wp   : K2*C*O   =    36,864
    //   owp  : C*27*9   =    15,552
    float* off_buf  = (float*)d_ws;
    float* mask_buf = off_buf + (size_t)B_ * 18 * HW_;
    float* wp       = mask_buf + (size_t)B_ * 9 * HW_;
    float* owp      = wp + (size_t)K2_ * C_ * O_;

    repack_weights<<<(O_ * C_ * K2_ + C_ * 27 * 9 + 255) / 256, 256, 0, stream>>>(
        weight, offset_w, mod_w, wp, owp);

    // K1: 64 pixels per block x 4 c-groups
    conv_offsets_mask<<<(B_ * HW_) / 64, 256, 0, stream>>>(
        x, owp, offset_b, mod_b, off_buf, mask_buf);

    // K2: 64 pixels per block x 2 o-halves x 2 c-halves
    deform_conv<<<(B_ * HW_) / 64, 256, 0, stream>>>(
        x, off_buf, mask_buf, wp, out);
}

// Round 4
// 135.806 us; speedup vs baseline: 2.6318x; 1.9124x over previous
//
#include <hip/hip_runtime.h>
#include <hip/hip_bf16.h>
#include <math.h>

typedef unsigned short u16;
typedef __attribute__((ext_vector_type(8))) short short8;
typedef __attribute__((ext_vector_type(4))) float f32x4;

// Problem constants
#define B_  4
#define C_  64
#define H_  128
#define W_  128
#define O_  64
#define HW_ (H_ * W_)
#define TP  32            // pixels per block
#define NPAIR (9 * TP)    // 288 (tap, pixel) pairs per block

__device__ __forceinline__ u16 f2bf(float f) {
    __hip_bfloat16 h = __float2bfloat16(f);
    u16 u; __builtin_memcpy(&u, &h, 2); return u;
}
__device__ __forceinline__ float bf2f(u16 u) {
    return __uint_as_float((unsigned)u << 16);
}

// -------------------------------------------------------------------------
// repack: Wb  (4 otile,18 ks,64 lane,8 j) bf16  from weight (O,C,3,3)
//         OWb (2 otile,18 ks,64 lane,8 j) bf16  from ow|mw|0
// K index convention: kidx = tap*64 + c  (tap-major, channel minor)
// A-frag (16x16x32): lane l holds A[o = l&15][k = ks*32 + (l>>4)*8 + j]
// -------------------------------------------------------------------------
__global__ __launch_bounds__(256) void repack(
    const float* __restrict__ weight,
    const float* __restrict__ ow, const float* __restrict__ mw,
    u16* __restrict__ Wb, u16* __restrict__ OWb)
{
    int t = blockIdx.x * 256 + threadIdx.x;      // 216 blocks = 55296 threads
    if (t < 36864) {                             // Wb
        int e = t;
        int j = e & 7, ln = (e >> 3) & 63;
        int ks = (e >> 9) % 18, ot = e / 9216;
        int o = ot * 16 + (ln & 15);
        int kidx = ks * 32 + ((ln >> 4) << 3) + j;
        int k = kidx >> 6, c = kidx & 63;
        Wb[e] = f2bf(weight[((size_t)(o * 64 + c)) * 9 + k]);
    } else {                                     // OWb
        int e = t - 36864;
        int j = e & 7, ln = (e >> 3) & 63;
        int ks = (e >> 9) % 18, ot = e / 9216;
        int o = ot * 16 + (ln & 15);
        int kidx = ks * 32 + ((ln >> 4) << 3) + j;
        int k = kidx >> 6, c = kidx & 63;
        float v = 0.0f;
        if (o < 18)      v = ow[((size_t)(o * 64 + c)) * 9 + k];
        else if (o < 27) v = mw[((size_t)((o - 18) * 64 + c)) * 9 + k];
        OWb[e] = f2bf(v);
    }
}

// -------------------------------------------------------------------------
// prep_t: transpose 2 batches of x (B,C,H,W) f32 -> xt (2,H,W,C) bf16
// -------------------------------------------------------------------------
__global__ __launch_bounds__(256) void prep_t(
    const float* __restrict__ x, u16* __restrict__ xt, int b0)
{
    __shared__ float tile[64][65];
    int i = blockIdx.x, t = threadIdx.x;        // 512 blocks
    int lb = i >> 8;                            // 0..1
    int gb = b0 + lb;
    int pix0 = (i & 255) << 6;
    const float* xb = x + ((size_t)gb << 20);   // gb * C*HW
#pragma unroll
    for (int it = 0; it < 16; ++it) {
        int e = it * 256 + t;
        int c = e >> 6, pl = e & 63;
        tile[c][pl] = xb[((size_t)c << 14) + pix0 + pl];
    }
    __syncthreads();
    u16* xo = xt + ((((size_t)lb << 14) + pix0) << 6);
#pragma unroll
    for (int it = 0; it < 16; ++it) {
        int e = it * 256 + t;
        int c = e & 63, pl = e >> 6;
        xo[((size_t)pl << 6) + c] = f2bf(tile[c][pl]);
    }
}

// -------------------------------------------------------------------------
// fused_dcn: block = 32 pixels (one row segment), 4 waves, lanes = channels.
//   phase 0: stage zero-padded 3x3 im2col S[32][576] (bf16, stride 584)
//   mfma K1: (M=32:[18 off + 9 mask + 5 pad]) x (K=576) -> param[27][32] LDS
//   step 1 : per-pair bilinear params (corner offsets + weights) -> LDS
//   step 2 : gather 4 coalesced corners per (tap,pix), rebuild S
//   mfma K2: (M=64) x (K=576) -> out
// Covers 2 batches (local lb = bid>>9), global batch = b0 + lb.
// -------------------------------------------------------------------------
__global__ __launch_bounds__(256) void fused_dcn(
    const u16* __restrict__ xt,
    const u16* __restrict__ Wb, const u16* __restrict__ OWb,
    const float* __restrict__ ob, const float* __restrict__ mb,
    float* __restrict__ out, int b0)
{
    __shared__ __align__(16) u16 S[TP][584];   // 37376 B (584 = 576 + 8 pad)
    __shared__ float param[27][TP];            //  3456 B
    __shared__ int4   pwo[NPAIR];              //  4608 B (corner element offsets)
    __shared__ float4 pww[NPAIR];              //  4608 B (bilinear*mask weights)

    const int t = threadIdx.x;
    const int lane = t & 63;
    const int wv = t >> 6;

    const int bid = blockIdx.x;                // 1024 blocks
    const int lb = bid >> 9;                   // 0..1 (local batch in xt)
    const int gb = b0 + lb;                    // global batch
    const int pix0 = (bid & 511) * TP;
    const int h  = pix0 >> 7;                  // all 32 pixels share one row
    const int w0 = pix0 & 127;

    const u16* xtb = xt + ((size_t)lb << 20);  // lb * HW * C

    // ---- phase 0: im2col staging (zero-padded taps), pure bf16 copy ----
    for (int pi = 0; pi < NPAIR / 4; ++pi) {
        int p = wv * (NPAIR / 4) + pi;
        int k = p >> 5, pixl = p & 31;
        int ky = k / 3, kx = k - 3 * ky;
        int y = h - 1 + ky;
        int xx = w0 + pixl - 1 + kx;
        u16 v = 0;
        if (((unsigned)y < (unsigned)H_) && ((unsigned)xx < (unsigned)W_))
            v = xtb[((((size_t)y << 7) + xx) << 6) + lane];
        S[pixl][k * 64 + lane] = v;
    }
    __syncthreads();

    // ---- MFMA K1: offset/mask conv, M=32 (2 otiles) x N=32 (2 pixtiles) ----
    {
        int ot = wv & 1, pt = wv >> 1;
        f32x4 acc = {0.f, 0.f, 0.f, 0.f};
        int brow = pt * 16 + (lane & 15);
        int bk = (lane >> 4) << 3;
#pragma unroll
        for (int ks = 0; ks < 18; ++ks) {
            short8 a = ((const short8*)OWb)[(ot * 18 + ks) * 64 + lane];
            short8 bf = *(const short8*)&S[brow][ks * 32 + bk];
            acc = __builtin_amdgcn_mfma_f32_16x16x32_bf16(a, bf, acc, 0, 0, 0);
        }
        int pix = pt * 16 + (lane & 15);
#pragma unroll
        for (int r = 0; r < 4; ++r) {
            int oc = ot * 16 + ((lane >> 4) << 2) + r;
            if (oc < 18) {
                param[oc][pix] = acc[r] + ob[oc];
            } else if (oc < 27) {
                float s = acc[r] + mb[oc - 18];
                param[oc][pix] = 2.0f / (1.0f + __expf(-s));
            }
        }
    }
    __syncthreads();

    // ---- step 1: bilinear params per (tap, pixel) pair ----
    for (int p = t; p < NPAIR; p += 256) {
        int k = p >> 5, pixl = p & 31;
        int ky = k / 3, kx = k - 3 * ky;
        float dy = param[2 * k][pixl];
        float dx = param[2 * k + 1][pixl];
        float m  = param[18 + k][pixl];
        float py = (float)(h - 1 + ky) + dy;
        float px = (float)(w0 + pixl - 1 + kx) + dx;
        float y0f = floorf(py), x0f = floorf(px);
        float fy = py - y0f, fx = px - x0f;
        int y0 = (int)y0f, x0 = (int)x0f;
        int y1 = y0 + 1, x1 = x0 + 1;
        bool vy0 = (unsigned)y0 < (unsigned)H_;
        bool vy1 = (unsigned)y1 < (unsigned)H_;
        bool vx0 = (unsigned)x0 < (unsigned)W_;
        bool vx1 = (unsigned)x1 < (unsigned)W_;
        float w00 = (1.f - fy) * (1.f - fx) * m; if (!(vy0 && vx0)) w00 = 0.f;
        float w01 = (1.f - fy) * fx          * m; if (!(vy0 && vx1)) w01 = 0.f;
        float w10 = fy * (1.f - fx)          * m; if (!(vy1 && vx0)) w10 = 0.f;
        float w11 = fy * fx                   * m; if (!(vy1 && vx1)) w11 = 0.f;
        int y0c = min(max(y0, 0), H_ - 1);
        int y1c = min(max(y1, 0), H_ - 1);
        int x0c = min(max(x0, 0), W_ - 1);
        int x1c = min(max(x1, 0), W_ - 1);
        int4 o4;
        o4.x = ((y0c << 7) + x0c) << 6;
        o4.y = ((y0c << 7) + x1c) << 6;
        o4.z = ((y1c << 7) + x0c) << 6;
        o4.w = ((y1c << 7) + x1c) << 6;
        pwo[p] = o4;
        float4 w4; w4.x = w00; w4.y = w01; w4.z = w10; w4.w = w11;
        pww[p] = w4;
    }
    __syncthreads();

    // ---- step 2: deformable gather, rebuild S (lanes = channels) ----
    for (int pi = 0; pi < NPAIR / 4; ++pi) {
        int p = wv * (NPAIR / 4) + pi;
        int k = p >> 5, pixl = p & 31;
        int4 o4 = pwo[p];          // uniform LDS broadcast
        float4 w4 = pww[p];
        float v00 = bf2f(xtb[o4.x + lane]);
        float v01 = bf2f(xtb[o4.y + lane]);
        float v10 = bf2f(xtb[o4.z + lane]);
        float v11 = bf2f(xtb[o4.w + lane]);
        float s = v00 * w4.x;
        s = fmaf(v01, w4.y, s);
        s = fmaf(v10, w4.z, s);
        s = fmaf(v11, w4.w, s);
        S[pixl][k * 64 + lane] = f2bf(s);
    }
    __syncthreads();

    // ---- MFMA K2: main contraction, M=64 (wave = otile) x N=32 ----
    {
        f32x4 acc0 = {0.f, 0.f, 0.f, 0.f};
        f32x4 acc1 = {0.f, 0.f, 0.f, 0.f};
        int brow = lane & 15;
        int bk = (lane >> 4) << 3;
#pragma unroll
        for (int ks = 0; ks < 18; ++ks) {
            short8 a = ((const short8*)Wb)[(wv * 18 + ks) * 64 + lane];
            short8 b0f = *(const short8*)&S[brow][ks * 32 + bk];
            short8 b1f = *(const short8*)&S[16 + brow][ks * 32 + bk];
            acc0 = __builtin_amdgcn_mfma_f32_16x16x32_bf16(a, b0f, acc0, 0, 0, 0);
            acc1 = __builtin_amdgcn_mfma_f32_16x16x32_bf16(a, b1f, acc1, 0, 0, 0);
        }
        float* op = out + (((size_t)gb << 6) << 14) + pix0;
#pragma unroll
        for (int r = 0; r < 4; ++r) {
            int o = wv * 16 + ((lane >> 4) << 2) + r;
            op[((size_t)o << 14) + (lane & 15)]      = acc0[r];
            op[((size_t)o << 14) + 16 + (lane & 15)] = acc1[r];
        }
    }
}

// -------------------------------------------------------------------------
extern "C" void kernel_launch(void* const* d_in, const int* in_sizes, int n_in,
                              void* d_out, int out_size, void* d_ws, size_t ws_size,
                              hipStream_t stream)
{
    const float* x        = (const float*)d_in[0];
    const float* offset_w = (const float*)d_in[1];
    const float* offset_b = (const float*)d_in[2];
    const float* mod_w    = (const float*)d_in[3];
    const float* mod_b    = (const float*)d_in[4];
    const float* weight   = (const float*)d_in[5];
    float* out = (float*)d_out;

    // Workspace (u16), total ~4.2 MiB (well under the proven-safe 7.35 MB):
    //   Wb  : 36864  (73,728 B)
    //   OWb : 18432  (36,864 B)
    //   xt  : 2 batches * HW * C = 2,097,152 u16 (4 MiB), reused per half
    u16* Wb  = (u16*)d_ws;
    u16* OWb = Wb + 36864;
    u16* xt  = OWb + 18432;

    repack<<<216, 256, 0, stream>>>(weight, offset_w, mod_w, Wb, OWb);

    // half 1: batches 0,1
    prep_t<<<512, 256, 0, stream>>>(x, xt, 0);
    fused_dcn<<<1024, 256, 0, stream>>>(xt, Wb, OWb, offset_b, mod_b, out, 0);

    // half 2: batches 2,3
    prep_t<<<512, 256, 0, stream>>>(x, xt, 2);
    fused_dcn<<<1024, 256, 0, stream>>>(xt, Wb, OWb, offset_b, mod_b, out, 2);
}

// Round 5
// 88.709 us; speedup vs baseline: 4.0290x; 1.5309x over previous
//
#include <hip/hip_runtime.h>
#include <hip/hip_bf16.h>
#include <math.h>

typedef unsigned short u16;
typedef unsigned int   u32;
typedef __attribute__((ext_vector_type(8))) short short8;
typedef __attribute__((ext_vector_type(4))) float f32x4;

// Problem constants
#define B_  4
#define C_  64
#define H_  128
#define W_  128
#define O_  64
#define HW_ (H_ * W_)
#define TP  16            // pixels per block
#define NPAIR (9 * TP)    // 144 (tap, pixel) pairs per block

__device__ __forceinline__ u16 f2bf(float f) {
    __hip_bfloat16 h = __float2bfloat16(f);
    u16 u; __builtin_memcpy(&u, &h, 2); return u;
}
__device__ __forceinline__ float bf2f(u16 u) {
    return __uint_as_float((u32)u << 16);
}

// -------------------------------------------------------------------------
// repack: Wb  (4 otile,18 ks,64 lane,8 j) bf16  from weight (O,C,3,3)
//         OWb (2 otile,18 ks,64 lane,8 j) bf16  from ow|mw|0
// K index convention: kidx = tap*64 + c  (tap-major, channel minor)
// A-frag (16x16x32): lane l holds A[o = l&15][k = ks*32 + (l>>4)*8 + j]
// -------------------------------------------------------------------------
__global__ __launch_bounds__(256) void repack(
    const float* __restrict__ weight,
    const float* __restrict__ ow, const float* __restrict__ mw,
    u16* __restrict__ Wb, u16* __restrict__ OWb)
{
    int t = blockIdx.x * 256 + threadIdx.x;      // 216 blocks = 55296 threads
    if (t < 36864) {                             // Wb
        int e = t;
        int j = e & 7, ln = (e >> 3) & 63;
        int ks = (e >> 9) % 18, ot = e / 9216;
        int o = ot * 16 + (ln & 15);
        int kidx = ks * 32 + ((ln >> 4) << 3) + j;
        int k = kidx >> 6, c = kidx & 63;
        Wb[e] = f2bf(weight[((size_t)(o * 64 + c)) * 9 + k]);
    } else {                                     // OWb
        int e = t - 36864;
        int j = e & 7, ln = (e >> 3) & 63;
        int ks = (e >> 9) % 18, ot = e / 9216;
        int o = ot * 16 + (ln & 15);
        int kidx = ks * 32 + ((ln >> 4) << 3) + j;
        int k = kidx >> 6, c = kidx & 63;
        float v = 0.0f;
        if (o < 18)      v = ow[((size_t)(o * 64 + c)) * 9 + k];
        else if (o < 27) v = mw[((size_t)((o - 18) * 64 + c)) * 9 + k];
        OWb[e] = f2bf(v);
    }
}

// -------------------------------------------------------------------------
// prep_t: transpose 2 batches of x (B,C,H,W) f32 -> xt (2,H,W,C) bf16
// -------------------------------------------------------------------------
__global__ __launch_bounds__(256) void prep_t(
    const float* __restrict__ x, u16* __restrict__ xt, int b0)
{
    __shared__ float tile[64][65];
    int i = blockIdx.x, t = threadIdx.x;        // 512 blocks
    int lb = i >> 8;                            // 0..1
    int gb = b0 + lb;
    int pix0 = (i & 255) << 6;
    const float* xb = x + ((size_t)gb << 20);   // gb * C*HW
#pragma unroll
    for (int it = 0; it < 16; ++it) {
        int e = it * 256 + t;
        int c = e >> 6, pl = e & 63;
        tile[c][pl] = xb[((size_t)c << 14) + pix0 + pl];
    }
    __syncthreads();
    u16* xo = xt + ((((size_t)lb << 14) + pix0) << 6);
#pragma unroll
    for (int it = 0; it < 16; ++it) {
        int e = it * 256 + t;
        int c = e & 63, pl = e >> 6;
        xo[((size_t)pl << 6) + c] = f2bf(tile[c][pl]);
    }
}

// -------------------------------------------------------------------------
// fused_dcn: block = 16 pixels (one row segment), 2 waves.
//   phase 0: stage zero-padded 3x3 im2col S[16][576] bf16, XOR-swizzled,
//            2 (tap,pix) pairs per wave-iter (lane = pair-half x chan-pair)
//   mfma K1: (M=32:[18 off + 9 mask + 5 pad]) x (K=576) -> param[27][16]
//   step 1 : per-pair bilinear corner positions (ushort4) + weights (bf16x4)
//   step 2 : gather 4 coalesced corners per pair (u32 = 2 ch), rebuild S
//   mfma K2: (M=64) x (K=576) -> out
// LDS = 18432 + 1728 + 1152 + 1152 = 22464 B -> 7 blocks/CU.
// -------------------------------------------------------------------------
__global__ __launch_bounds__(128) void fused_dcn(
    const u16* __restrict__ xt,
    const u16* __restrict__ Wb, const u16* __restrict__ OWb,
    const float* __restrict__ ob, const float* __restrict__ mb,
    float* __restrict__ out, int b0)
{
    __shared__ __align__(16) u16 S[TP][576];   // 18432 B, col ^ ((pixl&7)<<3)
    __shared__ float   param[27][TP];          //  1728 B
    __shared__ ushort4 pwp[NPAIR];             //  1152 B (corner positions)
    __shared__ ushort4 pww[NPAIR];             //  1152 B (bf16 bilinear*mask wts)

    const int t = threadIdx.x;
    const int lane = t & 63;
    const int wv = t >> 6;          // 0..1
    const int c2 = lane & 31;       // channel pair index (channels 2c2, 2c2+1)
    const int ph = lane >> 5;       // which of the 2 pairs this half-wave does

    int bid0 = blockIdx.x;          // 2048 blocks
    const int bid = (bid0 & 7) * 256 + (bid0 >> 3);   // XCD swizzle (bijective)
    const int lb = bid >> 10;       // 0..1 (local batch in xt)
    const int gb = b0 + lb;         // global batch
    const int pix0 = (bid & 1023) * TP;
    const int h  = pix0 >> 7;       // all 16 pixels share one row
    const int w0 = pix0 & 127;

    const u32* x32 = (const u32*)xt + ((size_t)lb << 19);   // lb * HW*C/2

    // ---- phase 0: im2col staging, 2 pairs per wave-iter, u32 (2ch) loads ----
#pragma unroll 4
    for (int pi = 0; pi < 36; ++pi) {
        int p = wv * 72 + (pi << 1) + ph;
        int k = p >> 4, pixl = p & 15;
        int ky = k / 3, kx = k - 3 * ky;
        int y = h - 1 + ky;
        int xx = w0 + pixl - 1 + kx;
        u32 v = 0;
        if (((unsigned)y < (unsigned)H_) && ((unsigned)xx < (unsigned)W_))
            v = x32[(((y << 7) + xx) << 5) + c2];
        *(u32*)&S[pixl][k * 64 + ((c2 << 1) ^ ((pixl & 7) << 3))] = v;
    }
    __syncthreads();

    // ---- MFMA K1: offset/mask conv, M=32 (wave=otile) x N=16 ----
    {
        f32x4 acc = {0.f, 0.f, 0.f, 0.f};
        int brow = lane & 15;
        int hi = lane >> 4;
        int swz = (brow & 7) << 3;
#pragma unroll
        for (int ks = 0; ks < 18; ++ks) {
            short8 a = ((const short8*)OWb)[(wv * 18 + ks) * 64 + lane];
            int tap = ks >> 1;
            int coff = ((ks & 1) << 5) + (hi << 3);
            short8 bf = *(const short8*)&S[brow][tap * 64 + (coff ^ swz)];
            acc = __builtin_amdgcn_mfma_f32_16x16x32_bf16(a, bf, acc, 0, 0, 0);
        }
        int pix = lane & 15;
#pragma unroll
        for (int r = 0; r < 4; ++r) {
            int oc = wv * 16 + (hi << 2) + r;
            if (oc < 18) {
                param[oc][pix] = acc[r] + ob[oc];
            } else if (oc < 27) {
                float s = acc[r] + mb[oc - 18];
                param[oc][pix] = 2.0f / (1.0f + __expf(-s));
            }
        }
    }
    __syncthreads();

    // ---- step 1: bilinear params per (tap, pixel) pair ----
    for (int p = t; p < NPAIR; p += 128) {
        int k = p >> 4, pixl = p & 15;
        int ky = k / 3, kx = k - 3 * ky;
        float dy = param[2 * k][pixl];
        float dx = param[2 * k + 1][pixl];
        float m  = param[18 + k][pixl];
        float py = (float)(h - 1 + ky) + dy;
        float px = (float)(w0 + pixl - 1 + kx) + dx;
        float y0f = floorf(py), x0f = floorf(px);
        float fy = py - y0f, fx = px - x0f;
        int y0 = (int)y0f, x0 = (int)x0f;
        int y1 = y0 + 1, x1 = x0 + 1;
        bool vy0 = (unsigned)y0 < (unsigned)H_;
        bool vy1 = (unsigned)y1 < (unsigned)H_;
        bool vx0 = (unsigned)x0 < (unsigned)W_;
        bool vx1 = (unsigned)x1 < (unsigned)W_;
        float w00 = (1.f - fy) * (1.f - fx) * m; if (!(vy0 && vx0)) w00 = 0.f;
        float w01 = (1.f - fy) * fx          * m; if (!(vy0 && vx1)) w01 = 0.f;
        float w10 = fy * (1.f - fx)          * m; if (!(vy1 && vx0)) w10 = 0.f;
        float w11 = fy * fx                   * m; if (!(vy1 && vx1)) w11 = 0.f;
        int y0c = min(max(y0, 0), H_ - 1);
        int y1c = min(max(y1, 0), H_ - 1);
        int x0c = min(max(x0, 0), W_ - 1);
        int x1c = min(max(x1, 0), W_ - 1);
        pwp[p] = make_ushort4((u16)((y0c << 7) + x0c), (u16)((y0c << 7) + x1c),
                              (u16)((y1c << 7) + x0c), (u16)((y1c << 7) + x1c));
        pww[p] = make_ushort4(f2bf(w00), f2bf(w01), f2bf(w10), f2bf(w11));
    }
    __syncthreads();

    // ---- step 2: deformable gather, 2 pairs per wave-iter, u32 loads ----
#pragma unroll 4
    for (int pi = 0; pi < 36; ++pi) {
        int p = wv * 72 + (pi << 1) + ph;
        int k = p >> 4, pixl = p & 15;
        ushort4 o4 = pwp[p];
        ushort4 wb4 = pww[p];
        float w00 = bf2f(wb4.x), w01 = bf2f(wb4.y);
        float w10 = bf2f(wb4.z), w11 = bf2f(wb4.w);
        u32 v00 = x32[((int)o4.x << 5) + c2];
        u32 v01 = x32[((int)o4.y << 5) + c2];
        u32 v10 = x32[((int)o4.z << 5) + c2];
        u32 v11 = x32[((int)o4.w << 5) + c2];
        float slo = bf2f((u16)v00) * w00;
        slo = fmaf(bf2f((u16)v01), w01, slo);
        slo = fmaf(bf2f((u16)v10), w10, slo);
        slo = fmaf(bf2f((u16)v11), w11, slo);
        float shi = bf2f((u16)(v00 >> 16)) * w00;
        shi = fmaf(bf2f((u16)(v01 >> 16)), w01, shi);
        shi = fmaf(bf2f((u16)(v10 >> 16)), w10, shi);
        shi = fmaf(bf2f((u16)(v11 >> 16)), w11, shi);
        u32 pk = ((u32)f2bf(shi) << 16) | (u32)f2bf(slo);
        *(u32*)&S[pixl][k * 64 + ((c2 << 1) ^ ((pixl & 7) << 3))] = pk;
    }
    __syncthreads();

    // ---- MFMA K2: main contraction, M=64 (wave = 2 otiles) x N=16 ----
    {
        f32x4 acc0 = {0.f, 0.f, 0.f, 0.f};
        f32x4 acc1 = {0.f, 0.f, 0.f, 0.f};
        int brow = lane & 15;
        int hi = lane >> 4;
        int swz = (brow & 7) << 3;
#pragma unroll
        for (int ks = 0; ks < 18; ++ks) {
            int tap = ks >> 1;
            int coff = ((ks & 1) << 5) + (hi << 3);
            short8 bfr = *(const short8*)&S[brow][tap * 64 + (coff ^ swz)];
            short8 a0 = ((const short8*)Wb)[((wv * 2) * 18 + ks) * 64 + lane];
            short8 a1 = ((const short8*)Wb)[((wv * 2 + 1) * 18 + ks) * 64 + lane];
            acc0 = __builtin_amdgcn_mfma_f32_16x16x32_bf16(a0, bfr, acc0, 0, 0, 0);
            acc1 = __builtin_amdgcn_mfma_f32_16x16x32_bf16(a1, bfr, acc1, 0, 0, 0);
        }
        float* op = out + ((size_t)gb << 20) + pix0;
#pragma unroll
        for (int r = 0; r < 4; ++r) {
            int o0 = (wv * 2) * 16 + (hi << 2) + r;
            int o1 = (wv * 2 + 1) * 16 + (hi << 2) + r;
            op[((size_t)o0 << 14) + (lane & 15)] = acc0[r];
            op[((size_t)o1 << 14) + (lane & 15)] = acc1[r];
        }
    }
}

// -------------------------------------------------------------------------
extern "C" void kernel_launch(void* const* d_in, const int* in_sizes, int n_in,
                              void* d_out, int out_size, void* d_ws, size_t ws_size,
                              hipStream_t stream)
{
    const float* x        = (const float*)d_in[0];
    const float* offset_w = (const float*)d_in[1];
    const float* offset_b = (const float*)d_in[2];
    const float* mod_w    = (const float*)d_in[3];
    const float* mod_b    = (const float*)d_in[4];
    const float* weight   = (const float*)d_in[5];
    float* out = (float*)d_out;

    // Workspace (u16), total ~4.2 MiB:
    //   Wb  : 36864 | OWb : 18432 | xt : 2 batches * HW * C = 2,097,152
    u16* Wb  = (u16*)d_ws;
    u16* OWb = Wb + 36864;
    u16* xt  = OWb + 18432;

    repack<<<216, 256, 0, stream>>>(weight, offset_w, mod_w, Wb, OWb);

    // half 1: batches 0,1
    prep_t<<<512, 256, 0, stream>>>(x, xt, 0);
    fused_dcn<<<2048, 128, 0, stream>>>(xt, Wb, OWb, offset_b, mod_b, out, 0);

    // half 2: batches 2,3
    prep_t<<<512, 256, 0, stream>>>(x, xt, 2);
    fused_dcn<<<2048, 128, 0, stream>>>(xt, Wb, OWb, offset_b, mod_b, out, 2);
}

// Round 6
// 65.050 us; speedup vs baseline: 5.4944x; 1.3637x over previous
//
#include <hip/hip_runtime.h>
#include <hip/hip_bf16.h>
#include <math.h>

typedef unsigned short u16;
typedef unsigned int   u32;
typedef __attribute__((ext_vector_type(8))) short short8;
typedef __attribute__((ext_vector_type(4))) float f32x4;

// Problem constants
#define B_  4
#define C_  64
#define H_  128
#define W_  128
#define O_  64
#define HW_ (H_ * W_)
#define TP  16            // pixels per block
#define NPAIR (9 * TP)    // 144 (tap, pixel) pairs per block

__device__ __forceinline__ u16 f2bf(float f) {
    __hip_bfloat16 h = __float2bfloat16(f);
    u16 u; __builtin_memcpy(&u, &h, 2); return u;
}
__device__ __forceinline__ float bf2f(u16 u) {
    return __uint_as_float((u32)u << 16);
}

// -------------------------------------------------------------------------
// repack: Wb  (4 otile,18 ks,64 lane,8 j) bf16  from weight (O,C,3,3)
//         OWb (2 otile,18 ks,64 lane,8 j) bf16  from ow|mw|0
// K index convention: kidx = tap*64 + c  (tap-major, channel minor)
// A-frag (16x16x32): lane l holds A[o = l&15][k = ks*32 + (l>>4)*8 + j]
// -------------------------------------------------------------------------
__global__ __launch_bounds__(256) void repack(
    const float* __restrict__ weight,
    const float* __restrict__ ow, const float* __restrict__ mw,
    u16* __restrict__ Wb, u16* __restrict__ OWb)
{
    int t = blockIdx.x * 256 + threadIdx.x;      // 216 blocks = 55296 threads
    if (t < 36864) {                             // Wb
        int e = t;
        int j = e & 7, ln = (e >> 3) & 63;
        int ks = (e >> 9) % 18, ot = e / 9216;
        int o = ot * 16 + (ln & 15);
        int kidx = ks * 32 + ((ln >> 4) << 3) + j;
        int k = kidx >> 6, c = kidx & 63;
        Wb[e] = f2bf(weight[((size_t)(o * 64 + c)) * 9 + k]);
    } else {                                     // OWb
        int e = t - 36864;
        int j = e & 7, ln = (e >> 3) & 63;
        int ks = (e >> 9) % 18, ot = e / 9216;
        int o = ot * 16 + (ln & 15);
        int kidx = ks * 32 + ((ln >> 4) << 3) + j;
        int k = kidx >> 6, c = kidx & 63;
        float v = 0.0f;
        if (o < 18)      v = ow[((size_t)(o * 64 + c)) * 9 + k];
        else if (o < 27) v = mw[((size_t)((o - 18) * 64 + c)) * 9 + k];
        OWb[e] = f2bf(v);
    }
}

// -------------------------------------------------------------------------
// prep_t: transpose all 4 batches of x (B,C,H,W) f32 -> xt (B,H,W,C) bf16
// -------------------------------------------------------------------------
__global__ __launch_bounds__(256) void prep_t(
    const float* __restrict__ x, u16* __restrict__ xt)
{
    __shared__ float tile[64][65];
    int i = blockIdx.x, t = threadIdx.x;        // 1024 blocks
    int lb = i >> 8;                            // 0..3
    int pix0 = (i & 255) << 6;
    const float* xb = x + ((size_t)lb << 20);   // lb * C*HW
#pragma unroll
    for (int it = 0; it < 16; ++it) {
        int e = it * 256 + t;
        int c = e >> 6, pl = e & 63;
        tile[c][pl] = xb[((size_t)c << 14) + pix0 + pl];
    }
    __syncthreads();
    u16* xo = xt + ((((size_t)lb << 14) + pix0) << 6);
#pragma unroll
    for (int it = 0; it < 16; ++it) {
        int e = it * 256 + t;
        int c = e & 63, pl = e >> 6;
        xo[((size_t)pl << 6) + c] = f2bf(tile[c][pl]);
    }
}

// -------------------------------------------------------------------------
// fused_dcn: block = 16 pixels (one row segment), 4 waves.
//   phase 0: stage zero-padded 3x3 im2col S[16][576] bf16, XOR-swizzled,
//            2 (tap,pix) pairs per wave-iter (lane = pair-half x chan-pair)
//   mfma K1: waves 0,1: (M=32:[18 off+9 mask+5 pad]) x (K=576) -> param[27][16]
//   step 1 : per-pair bilinear corner positions (ushort4) + weights (bf16x4)
//   step 2 : gather 4 coalesced corners per pair (u32 = 2 ch), rebuild S
//   mfma K2: (M=64, wave = 1 otile) x (K=576) -> out
// LDS = 18432 + 1728 + 1152 + 1152 = 22464 B -> 7 blocks/CU, 28 waves/CU.
// -------------------------------------------------------------------------
__global__ __launch_bounds__(256, 6) void fused_dcn(
    const u16* __restrict__ xt,
    const u16* __restrict__ Wb, const u16* __restrict__ OWb,
    const float* __restrict__ ob, const float* __restrict__ mb,
    float* __restrict__ out)
{
    __shared__ __align__(16) u16 S[TP][576];   // 18432 B, col ^ ((pixl&7)<<3)
    __shared__ float   param[27][TP];          //  1728 B
    __shared__ ushort4 pwp[NPAIR];             //  1152 B (corner positions)
    __shared__ ushort4 pww[NPAIR];             //  1152 B (bf16 bilinear*mask wts)

    const int t = threadIdx.x;
    const int lane = t & 63;
    const int wv = t >> 6;          // 0..3
    const int c2 = lane & 31;       // channel pair index (channels 2c2, 2c2+1)
    const int ph = lane >> 5;       // which of the 2 pairs this half-wave does

    int bid0 = blockIdx.x;          // 4096 blocks
    const int bid = (bid0 & 7) * 512 + (bid0 >> 3);   // XCD swizzle (bijective)
    const int lb = bid >> 10;       // batch 0..3
    const int pix0 = (bid & 1023) * TP;
    const int h  = pix0 >> 7;       // all 16 pixels share one row
    const int w0 = pix0 & 127;

    const u32* x32 = (const u32*)xt + ((size_t)lb << 19);   // lb * HW*C/2

    // ---- phase 0: im2col staging, 2 pairs per wave-iter, u32 (2ch) loads ----
#pragma unroll 4
    for (int pi = 0; pi < 18; ++pi) {
        int p = wv * 36 + (pi << 1) + ph;
        int k = p >> 4, pixl = p & 15;
        int ky = k / 3, kx = k - 3 * ky;
        int y = h - 1 + ky;
        int xx = w0 + pixl - 1 + kx;
        u32 v = 0;
        if (((unsigned)y < (unsigned)H_) && ((unsigned)xx < (unsigned)W_))
            v = x32[(((y << 7) + xx) << 5) + c2];
        *(u32*)&S[pixl][k * 64 + ((c2 << 1) ^ ((pixl & 7) << 3))] = v;
    }
    __syncthreads();

    // ---- MFMA K1: offset/mask conv, M=32 (waves 0,1 = otile) x N=16 ----
    if (wv < 2) {
        f32x4 acc = {0.f, 0.f, 0.f, 0.f};
        int brow = lane & 15;
        int hi = lane >> 4;
        int swz = (brow & 7) << 3;
#pragma unroll
        for (int ks = 0; ks < 18; ++ks) {
            short8 a = ((const short8*)OWb)[(wv * 18 + ks) * 64 + lane];
            int tap = ks >> 1;
            int coff = ((ks & 1) << 5) + (hi << 3);
            short8 bf = *(const short8*)&S[brow][tap * 64 + (coff ^ swz)];
            acc = __builtin_amdgcn_mfma_f32_16x16x32_bf16(a, bf, acc, 0, 0, 0);
        }
        int pix = lane & 15;
#pragma unroll
        for (int r = 0; r < 4; ++r) {
            int oc = wv * 16 + (hi << 2) + r;
            if (oc < 18) {
                param[oc][pix] = acc[r] + ob[oc];
            } else if (oc < 27) {
                float s = acc[r] + mb[oc - 18];
                param[oc][pix] = 2.0f / (1.0f + __expf(-s));
            }
        }
    }
    __syncthreads();

    // ---- step 1: bilinear params per (tap, pixel) pair ----
    if (t < NPAIR) {
        int p = t;
        int k = p >> 4, pixl = p & 15;
        int ky = k / 3, kx = k - 3 * ky;
        float dy = param[2 * k][pixl];
        float dx = param[2 * k + 1][pixl];
        float m  = param[18 + k][pixl];
        float py = (float)(h - 1 + ky) + dy;
        float px = (float)(w0 + pixl - 1 + kx) + dx;
        float y0f = floorf(py), x0f = floorf(px);
        float fy = py - y0f, fx = px - x0f;
        int y0 = (int)y0f, x0 = (int)x0f;
        int y1 = y0 + 1, x1 = x0 + 1;
        bool vy0 = (unsigned)y0 < (unsigned)H_;
        bool vy1 = (unsigned)y1 < (unsigned)H_;
        bool vx0 = (unsigned)x0 < (unsigned)W_;
        bool vx1 = (unsigned)x1 < (unsigned)W_;
        float w00 = (1.f - fy) * (1.f - fx) * m; if (!(vy0 && vx0)) w00 = 0.f;
        float w01 = (1.f - fy) * fx          * m; if (!(vy0 && vx1)) w01 = 0.f;
        float w10 = fy * (1.f - fx)          * m; if (!(vy1 && vx0)) w10 = 0.f;
        float w11 = fy * fx                   * m; if (!(vy1 && vx1)) w11 = 0.f;
        int y0c = min(max(y0, 0), H_ - 1);
        int y1c = min(max(y1, 0), H_ - 1);
        int x0c = min(max(x0, 0), W_ - 1);
        int x1c = min(max(x1, 0), W_ - 1);
        pwp[p] = make_ushort4((u16)((y0c << 7) + x0c), (u16)((y0c << 7) + x1c),
                              (u16)((y1c << 7) + x0c), (u16)((y1c << 7) + x1c));
        pww[p] = make_ushort4(f2bf(w00), f2bf(w01), f2bf(w10), f2bf(w11));
    }
    __syncthreads();

    // ---- step 2: deformable gather, 2 pairs per wave-iter, u32 loads ----
#pragma unroll 4
    for (int pi = 0; pi < 18; ++pi) {
        int p = wv * 36 + (pi << 1) + ph;
        int k = p >> 4, pixl = p & 15;
        ushort4 o4 = pwp[p];
        ushort4 wb4 = pww[p];
        float w00 = bf2f(wb4.x), w01 = bf2f(wb4.y);
        float w10 = bf2f(wb4.z), w11 = bf2f(wb4.w);
        u32 v00 = x32[((int)o4.x << 5) + c2];
        u32 v01 = x32[((int)o4.y << 5) + c2];
        u32 v10 = x32[((int)o4.z << 5) + c2];
        u32 v11 = x32[((int)o4.w << 5) + c2];
        float slo = bf2f((u16)v00) * w00;
        slo = fmaf(bf2f((u16)v01), w01, slo);
        slo = fmaf(bf2f((u16)v10), w10, slo);
        slo = fmaf(bf2f((u16)v11), w11, slo);
        float shi = bf2f((u16)(v00 >> 16)) * w00;
        shi = fmaf(bf2f((u16)(v01 >> 16)), w01, shi);
        shi = fmaf(bf2f((u16)(v10 >> 16)), w10, shi);
        shi = fmaf(bf2f((u16)(v11 >> 16)), w11, shi);
        u32 pk = ((u32)f2bf(shi) << 16) | (u32)f2bf(slo);
        *(u32*)&S[pixl][k * 64 + ((c2 << 1) ^ ((pixl & 7) << 3))] = pk;
    }
    __syncthreads();

    // ---- MFMA K2: main contraction, M=64 (wave = otile) x N=16 ----
    {
        f32x4 acc = {0.f, 0.f, 0.f, 0.f};
        int brow = lane & 15;
        int hi = lane >> 4;
        int swz = (brow & 7) << 3;
#pragma unroll
        for (int ks = 0; ks < 18; ++ks) {
            int tap = ks >> 1;
            int coff = ((ks & 1) << 5) + (hi << 3);
            short8 bfr = *(const short8*)&S[brow][tap * 64 + (coff ^ swz)];
            short8 a = ((const short8*)Wb)[(wv * 18 + ks) * 64 + lane];
            acc = __builtin_amdgcn_mfma_f32_16x16x32_bf16(a, bfr, acc, 0, 0, 0);
        }
        float* op = out + ((size_t)lb << 20) + pix0;
#pragma unroll
        for (int r = 0; r < 4; ++r) {
            int o = wv * 16 + (hi << 2) + r;
            op[((size_t)o << 14) + (lane & 15)] = acc[r];
        }
    }
}

// -------------------------------------------------------------------------
extern "C" void kernel_launch(void* const* d_in, const int* in_sizes, int n_in,
                              void* d_out, int out_size, void* d_ws, size_t ws_size,
                              hipStream_t stream)
{
    const float* x        = (const float*)d_in[0];
    const float* offset_w = (const float*)d_in[1];
    const float* offset_b = (const float*)d_in[2];
    const float* mod_w    = (const float*)d_in[3];
    const float* mod_b    = (const float*)d_in[4];
    const float* weight   = (const float*)d_in[5];
    float* out = (float*)d_out;

    // Workspace (u16), total ~8.1 MiB (ws_size ~= 256 MiB per harness fill):
    //   Wb  : 36864 | OWb : 18432 | xt : 4 batches * HW * C = 4,194,304
    u16* Wb  = (u16*)d_ws;
    u16* OWb = Wb + 36864;
    u16* xt  = OWb + 18432;

    repack<<<216, 256, 0, stream>>>(weight, offset_w, mod_w, Wb, OWb);
    prep_t<<<1024, 256, 0, stream>>>(x, xt);
    fused_dcn<<<4096, 256, 0, stream>>>(xt, Wb, OWb, offset_b, mod_b, out);
}